// Round 1
// baseline (892.176 us; speedup 1.0000x reference)
//
#include <hip/hip_runtime.h>
#include <math.h>

#define B 2
#define CK 64
#define CV 16
#define K_TOP 20
#define NSCALE 3

struct ScaleCfg {
  const float *kq, *vq, *km, *vm;
  float *asq, *score, *posw, *segv;
  int   *segi;
  float *e20; int *i20;
  float *Spart, *invS, *base, *out;
  int HW, NE, NSEG, seg_len, htiles;
};
struct AllCfg { ScaleCfg s[NSCALE]; };

__device__ __forceinline__ float gelu_exact(float x) {
  return 0.5f * x * (1.f + erff(x * 0.70710678118654752f));
}

// ---------------------------------------------------------------- PREP
// pooled -> channel MLP -> layernorm -> score MLP -> pos_w softmax.
// grid (B, 3), block 256.
__global__ __launch_bounds__(256) void prep_kernel(AllCfg all,
    const float* mw1, const float* mb1, const float* mw2, const float* mb2,
    const float* lng, const float* lnb,
    const float* pw1, const float* pb1, const float* pw2, const float* pb2)
{
  const int b = blockIdx.x, s = blockIdx.y;
  const ScaleCfg cfg = all.s[s];
  const int HW = cfg.HW;
  const float* vq = cfg.vq + (size_t)b * CV * HW;
  __shared__ float red[256];
  __shared__ float cw_s[CV];
  __shared__ float wk_s[CV][8];
  const int t = threadIdx.x;

  // P1: pooled[c] = mean over HW. 16 threads per channel.
  const int c16 = t >> 4, l16 = t & 15;
  float acc = 0.f;
  for (int h = l16; h < HW; h += 16) acc += vq[c16 * HW + h];
  red[t] = acc; __syncthreads();
  if (l16 < 8) red[t] += red[t + 8]; __syncthreads();
  if (l16 < 4) red[t] += red[t + 4]; __syncthreads();
  if (l16 < 2) red[t] += red[t + 2]; __syncthreads();
  if (l16 < 1) red[t] += red[t + 1]; __syncthreads();

  // P2: channel MLP (hidden dim = 1) + layernorm, serial on thread 0 (tiny).
  if (t == 0) {
    float invHW = 1.f / (float)HW;
    float h1 = mb1[s];
    #pragma unroll
    for (int c = 0; c < CV; c++) h1 += (red[c * 16] * invHW) * mw1[s * CV + c];
    float g = gelu_exact(h1);
    float cwv[CV]; float m = 0.f;
    #pragma unroll
    for (int c = 0; c < CV; c++) { cwv[c] = g * mw2[s * CV + c] + mb2[s * CV + c]; m += cwv[c]; }
    m *= (1.f / CV);
    float v = 0.f;
    #pragma unroll
    for (int c = 0; c < CV; c++) { float d = cwv[c] - m; v += d * d; }
    v *= (1.f / CV);
    float rs = 1.f / sqrtf(v + 1e-5f);
    #pragma unroll
    for (int c = 0; c < CV; c++)
      cw_s[c] = (cwv[c] - m) * rs * lng[s * CV + c] + lnb[s * CV + c];
  }
  __syncthreads();
  // premultiply cw into proj_w1
  if (t < CV * 8) {
    int c = t >> 3, k = t & 7;
    wk_s[c][k] = cw_s[c] * pw1[s * CV * 8 + c * 8 + k];
  }
  __syncthreads();

  // P3: score per position, z = score*10 (TEMP=0.1), track max
  float lmax = -INFINITY;
  for (int h = t; h < HW; h += 256) {
    float vqr[CV];
    #pragma unroll
    for (int c = 0; c < CV; c++) vqr[c] = vq[c * HW + h];
    float sc = pb2[s];
    #pragma unroll
    for (int k = 0; k < 8; k++) {
      float hv = pb1[s * 8 + k];
      #pragma unroll
      for (int c = 0; c < CV; c++) hv += vqr[c] * wk_s[c][k];
      sc += gelu_exact(hv) * pw2[s * 8 + k];
    }
    float z = sc * 10.f;
    cfg.score[b * HW + h] = z;
    lmax = fmaxf(lmax, z);
  }
  red[t] = lmax; __syncthreads();
  #pragma unroll
  for (int off = 128; off >= 1; off >>= 1) {
    if (t < off) red[t] = fmaxf(red[t], red[t + off]);
    __syncthreads();
  }
  const float zmax = red[0];
  __syncthreads();
  // P4: sum of exp
  float lsum = 0.f;
  for (int h = t; h < HW; h += 256) lsum += expf(cfg.score[b * HW + h] - zmax);
  red[t] = lsum; __syncthreads();
  #pragma unroll
  for (int off = 128; off >= 1; off >>= 1) {
    if (t < off) red[t] += red[t + off];
    __syncthreads();
  }
  const float inv_sum = 1.f / red[0];
  // P5: pos_w
  for (int h = t; h < HW; h += 256)
    cfg.posw[b * HW + h] = expf(cfg.score[b * HW + h] - zmax) * inv_sum;
}

// ---------------------------------------------------------------- ASQ
__global__ __launch_bounds__(256) void asq_kernel(ScaleCfg cfg) {
  const int NE = cfg.NE;
  int i = blockIdx.x * 256 + threadIdx.x;
  if (i >= B * NE) return;
  int b = i / NE, n = i - b * NE;
  const float* km = cfg.km + (size_t)b * CK * NE + n;
  float s = 0.f;
  #pragma unroll 8
  for (int c = 0; c < CK; c++) { float v = km[(size_t)c * NE]; s = fmaf(v, v, s); }
  cfg.asq[i] = s;
}

// ---------------------------------------------------------------- TOPK
// Fused aff-GEMM + exact per-column top-20.
// grid (htiles, NSEG, B), block 256 (4 waves). Tile: 64 cols x 64 rows/chunk.
#define SMEM_FLOATS 10240
__global__ __launch_bounds__(256) void topk_kernel(ScaleCfg cfg) {
  __shared__ float smem[SMEM_FLOATS];
  float (*qk_s)[64] = reinterpret_cast<float (*)[64]>(smem);          // [c][hh]
  float (*km_s)[64] = reinterpret_cast<float (*)[64]>(smem + 4096);   // [c][nn]
  float (*dot_s)[64] = km_s;                                          // [nn][hh] (reuse)
  float* asq_s = smem + 8192;

  const int HW = cfg.HW, NE = cfg.NE;
  const int hbase = blockIdx.x * 64;
  const int seg = blockIdx.y;
  const int b = blockIdx.z;
  const int n0 = seg * cfg.seg_len;
  const int n1 = min(n0 + cfg.seg_len, NE);
  const float* km = cfg.km + (size_t)b * CK * NE;
  const float* qk = cfg.kq + (size_t)b * CK * HW;

  const int t = threadIdx.x;
  const int tx = t & 15, ty = t >> 4;       // gemm micro-tile coords
  const int w = t >> 6, l = t & 63;         // scan coords

  // stage qk tile once
  for (int f = t; f < CK * 64; f += 256) {
    int c = f >> 6, hh = f & 63;
    int h = hbase + hh;
    qk_s[c][hh] = (h < HW) ? qk[(size_t)c * HW + h] : 0.f;
  }

  float tkv[K_TOP]; int tki[K_TOP];
  #pragma unroll
  for (int k = 0; k < K_TOP; k++) { tkv[k] = -INFINITY; tki[k] = 0x7fffffff; }
  __syncthreads();

  for (int nbase = n0; nbase < n1; nbase += 64) {
    // stage km chunk + asq
    for (int f = t; f < CK * 64; f += 256) {
      int c = f >> 6, nn = f & 63;
      int n = nbase + nn;
      km_s[c][nn] = (n < n1) ? km[(size_t)c * NE + n] : 0.f;
    }
    if (t < 64) asq_s[t] = (nbase + t < n1) ? cfg.asq[(size_t)b * NE + nbase + t] : 0.f;
    __syncthreads();

    // GEMM: 4x4 micro-tile per thread
    float accm[4][4];
    #pragma unroll
    for (int i = 0; i < 4; i++)
      #pragma unroll
      for (int j = 0; j < 4; j++) accm[i][j] = 0.f;
    #pragma unroll 4
    for (int c = 0; c < CK; c++) {
      float4 av = *reinterpret_cast<const float4*>(&km_s[c][4 * ty]);
      float4 bv = *reinterpret_cast<const float4*>(&qk_s[c][4 * tx]);
      float ar[4] = {av.x, av.y, av.z, av.w};
      float br[4] = {bv.x, bv.y, bv.z, bv.w};
      #pragma unroll
      for (int i = 0; i < 4; i++)
        #pragma unroll
        for (int j = 0; j < 4; j++) accm[i][j] = fmaf(ar[i], br[j], accm[i][j]);
    }
    __syncthreads();   // all km_s reads done
    #pragma unroll
    for (int i = 0; i < 4; i++)
      *reinterpret_cast<float4*>(&dot_s[4 * ty + i][4 * tx]) =
          make_float4(accm[i][0], accm[i][1], accm[i][2], accm[i][3]);
    __syncthreads();   // dots visible

    // scan: wave w owns rows w*16..w*16+15; lane l = column
    for (int q = 0; q < 16; q++) {
      int r = (w << 4) + q;
      int n = nbase + r;
      float d = dot_s[r][l];
      float aff = (2.f * d - asq_s[r]) * 0.125f;
      if (n < n1 && aff > tkv[K_TOP - 1]) {
        // static sorted insert (desc), ties keep existing (smaller n)
        float pv = 0.f; int pi = 0; bool pg = true;
        #pragma unroll
        for (int k = 0; k < K_TOP; k++) {
          bool g = (tkv[k] >= aff);
          float nv = g ? tkv[k] : (pg ? aff : pv);
          int   ni = g ? tki[k] : (pg ? n   : pi);
          pv = tkv[k]; pi = tki[k];
          tkv[k] = nv; tki[k] = ni; pg = g;
        }
      }
    }
    __syncthreads();   // scan done before next stage overwrites
  }

  // ---- in-block merge of the 4 wave-partials per column ----
  float* mv = smem;                                   // 4*64*20 floats
  int*   mi = reinterpret_cast<int*>(smem + 5120);    // 4*64*20 ints
  #pragma unroll
  for (int k = 0; k < K_TOP; k++) {
    mv[(w * 64 + l) * K_TOP + k] = tkv[k];
    mi[(w * 64 + l) * K_TOP + k] = tki[k];
  }
  __syncthreads();

  const int col = t >> 2, sub = t & 3;   // 4 threads cooperate per column
  #pragma unroll
  for (int k = 0; k < K_TOP; k++) {
    tkv[k] = mv[(sub * 64 + col) * K_TOP + k];
    tki[k] = mi[(sub * 64 + col) * K_TOP + k];
  }
  const int h = hbase + col;
  float* outv = cfg.segv + (((size_t)b * HW + h) * cfg.NSEG + seg) * K_TOP;
  int*   outi = cfg.segi + (((size_t)b * HW + h) * cfg.NSEG + seg) * K_TOP;
  const bool do_store = (sub == 0) && (h < HW);

  for (int pop = 0; pop < K_TOP; pop++) {
    float bv = tkv[0]; int bi = tki[0];
    #pragma unroll
    for (int k = 1; k < K_TOP; k++) {
      bool better = (tkv[k] > bv) || (tkv[k] == bv && tki[k] < bi);
      bv = better ? tkv[k] : bv; bi = better ? tki[k] : bi;
    }
    #pragma unroll
    for (int d2 = 1; d2 <= 2; d2 <<= 1) {
      float ov = __shfl_xor(bv, d2);
      int   oi = __shfl_xor(bi, d2);
      bool better = (ov > bv) || (ov == bv && oi < bi);
      bv = better ? ov : bv; bi = better ? oi : bi;
    }
    // destructive consume by (value,idx) match — unique idx, only owner matches
    #pragma unroll
    for (int k = 0; k < K_TOP; k++) {
      bool m = (tkv[k] == bv) && (tki[k] == bi);
      tkv[k] = m ? -INFINITY : tkv[k];
      tki[k] = m ? 0x7fffffff : tki[k];
    }
    if (do_store) { outv[pop] = bv; outi[pop] = bi; }
  }
}

// ---------------------------------------------------------------- MERGE
// Per column: merge NSEG partial top-20s -> exact top-20 -> softmax ->
// e_j = expm1(w_j * posw), atomic S accumulation. 1 wave per column.
__global__ __launch_bounds__(256) void merge_kernel(ScaleCfg cfg) {
  const int HW = cfg.HW, NE = cfg.NE, NSEG = cfg.NSEG;
  const int w = threadIdx.x >> 6, l = threadIdx.x & 63;
  const int colg = blockIdx.x * 4 + w;
  if (colg >= B * HW) return;
  const int b = colg / HW, h = colg - b * HW;
  const int NC = NSEG * K_TOP;   // <= 320

  const float* sv = cfg.segv + (size_t)colg * NC;
  const int*   si = cfg.segi + (size_t)colg * NC;
  float cv[5]; int ci[5];
  #pragma unroll
  for (int u = 0; u < 5; u++) {
    int slot = u * 64 + l;
    bool ok = slot < NC;
    cv[u] = ok ? sv[slot] : -INFINITY;
    ci[u] = ok ? si[slot] : 0x7fffffff;
  }

  float keepv = -INFINITY; int keepi = 0;
  for (int pop = 0; pop < K_TOP; pop++) {
    float bv = cv[0]; int bi = ci[0];
    #pragma unroll
    for (int u = 1; u < 5; u++) {
      bool better = (cv[u] > bv) || (cv[u] == bv && ci[u] < bi);
      bv = better ? cv[u] : bv; bi = better ? ci[u] : bi;
    }
    #pragma unroll
    for (int d = 1; d < 64; d <<= 1) {
      float ov = __shfl_xor(bv, d);
      int   oi = __shfl_xor(bi, d);
      bool better = (ov > bv) || (ov == bv && oi < bi);
      bv = better ? ov : bv; bi = better ? oi : bi;
    }
    #pragma unroll
    for (int u = 0; u < 5; u++) {
      bool m = (cv[u] == bv) && (ci[u] == bi);
      cv[u] = m ? -INFINITY : cv[u];
      ci[u] = m ? 0x7fffffff : ci[u];
    }
    if (l == pop) { keepv = bv; keepi = bi; }
  }

  // softmax over the 20 selected values (lane j holds j-th largest)
  float m = __shfl(keepv, 0);
  float e = (l < K_TOP) ? expf(keepv - m) : 0.f;
  float ssum = e;
  #pragma unroll
  for (int d = 1; d < 64; d <<= 1) ssum += __shfl_xor(ssum, d);
  float pw = cfg.posw[colg];
  if (l < K_TOP) {
    float wj = e / ssum;
    float ej = expm1f(wj * pw);
    cfg.e20[(size_t)colg * K_TOP + l] = ej;
    cfg.i20[(size_t)colg * K_TOP + l] = keepi;
    atomicAdd(&cfg.Spart[(size_t)b * NE + keepi], ej);
  }
}

// ---------------------------------------------------------------- INVS
__global__ __launch_bounds__(256) void invs_kernel(ScaleCfg cfg) {
  int i = blockIdx.x * 256 + threadIdx.x;
  if (i < B * cfg.NE) cfg.invS[i] = 1.f / ((float)cfg.HW + cfg.Spart[i]);
}

// ---------------------------------------------------------------- BASE
__global__ __launch_bounds__(256) void base_kernel(ScaleCfg cfg) {
  const int c = blockIdx.x, b = blockIdx.y;
  const int NE = cfg.NE;
  const float* vm = cfg.vm + ((size_t)b * CV + c) * NE;
  const float* invS = cfg.invS + (size_t)b * NE;
  float acc = 0.f;
  for (int n = threadIdx.x; n < NE; n += 256) acc += vm[n] * invS[n];
  __shared__ float red[256];
  const int t = threadIdx.x;
  red[t] = acc; __syncthreads();
  #pragma unroll
  for (int off = 128; off >= 1; off >>= 1) {
    if (t < off) red[t] += red[t + off];
    __syncthreads();
  }
  if (t == 0) cfg.base[b * CV + c] = red[0];
}

// ---------------------------------------------------------------- OUT
__global__ __launch_bounds__(256) void out_kernel(ScaleCfg cfg) {
  const int HW = cfg.HW;
  int idx = blockIdx.x * 256 + threadIdx.x;
  if (idx >= B * CV * HW) return;
  int h = idx % HW; int rest = idx / HW;
  int c = rest % CV; int b = rest / CV;
  const int*   i20 = cfg.i20 + ((size_t)(b * HW + h)) * K_TOP;
  const float* e20 = cfg.e20 + ((size_t)(b * HW + h)) * K_TOP;
  const float* vm = cfg.vm + ((size_t)b * CV + c) * cfg.NE;
  const float* invS = cfg.invS + (size_t)b * cfg.NE;
  float r = cfg.base[b * CV + c];
  #pragma unroll
  for (int j = 0; j < K_TOP; j++) {
    int n = i20[j];
    r += vm[n] * e20[j] * invS[n];
  }
  float* out = cfg.out;
  out[((size_t)b * 2 * CV + c) * HW + h] = r;
  out[((size_t)b * 2 * CV + CV + c) * HW + h] =
      cfg.vq[((size_t)b * CV + c) * HW + h];
}

// ---------------------------------------------------------------- host
extern "C" void kernel_launch(void* const* d_in, const int* in_sizes, int n_in,
                              void* d_out, int out_size, void* d_ws, size_t ws_size,
                              hipStream_t stream)
{
  (void)in_sizes; (void)n_in; (void)out_size; (void)ws_size;
  const float* kq[3] = {(const float*)d_in[0], (const float*)d_in[4], (const float*)d_in[8]};
  const float* vq[3] = {(const float*)d_in[1], (const float*)d_in[5], (const float*)d_in[9]};
  const float* km[3] = {(const float*)d_in[2], (const float*)d_in[6], (const float*)d_in[10]};
  const float* vm[3] = {(const float*)d_in[3], (const float*)d_in[7], (const float*)d_in[11]};
  const float* mw1 = (const float*)d_in[12];
  const float* mb1 = (const float*)d_in[13];
  const float* mw2 = (const float*)d_in[14];
  const float* mb2 = (const float*)d_in[15];
  const float* lng = (const float*)d_in[16];
  const float* lnb = (const float*)d_in[17];
  const float* pw1 = (const float*)d_in[18];
  const float* pb1 = (const float*)d_in[19];
  const float* pw2 = (const float*)d_in[20];
  const float* pb2 = (const float*)d_in[21];

  static const int HWs[3]   = {1936, 484, 121};
  static const int NEs[3]   = {15488, 3872, 968};
  static const int NSEGs[3] = {8, 16, 8};
  static const size_t outoff[3] = {0, 123904, 154880};

  char* ws = (char*)d_ws;
  size_t off = 0;
  auto alloc = [&](size_t nbytes) -> void* {
    void* p = ws + off;
    off += (nbytes + 255) & ~(size_t)255;
    return p;
  };

  AllCfg all;
  for (int s = 0; s < 3; s++) {
    ScaleCfg& c = all.s[s];
    c.kq = kq[s]; c.vq = vq[s]; c.km = km[s]; c.vm = vm[s];
    c.HW = HWs[s]; c.NE = NEs[s]; c.NSEG = NSEGs[s];
    c.seg_len = (c.NE + c.NSEG - 1) / c.NSEG;
    c.htiles = (c.HW + 63) / 64;
    const size_t bhw = (size_t)B * c.HW, bne = (size_t)B * c.NE;
    c.asq   = (float*)alloc(bne * 4);
    c.score = (float*)alloc(bhw * 4);
    c.posw  = (float*)alloc(bhw * 4);
    c.segv  = (float*)alloc(bhw * c.NSEG * K_TOP * 4);
    c.segi  = (int*)  alloc(bhw * c.NSEG * K_TOP * 4);
    c.e20   = (float*)alloc(bhw * K_TOP * 4);
    c.i20   = (int*)  alloc(bhw * K_TOP * 4);
    c.Spart = (float*)alloc(bne * 4);
    c.invS  = (float*)alloc(bne * 4);
    c.base  = (float*)alloc((size_t)B * CV * 4);
    c.out   = (float*)d_out + outoff[s];
  }

  for (int s = 0; s < 3; s++)
    hipMemsetAsync(all.s[s].Spart, 0, (size_t)B * NEs[s] * 4, stream);

  prep_kernel<<<dim3(B, 3), 256, 0, stream>>>(all, mw1, mb1, mw2, mb2,
                                              lng, lnb, pw1, pb1, pw2, pb2);
  for (int s = 0; s < 3; s++) {
    int g = (B * NEs[s] + 255) / 256;
    asq_kernel<<<g, 256, 0, stream>>>(all.s[s]);
  }
  for (int s = 0; s < 3; s++) {
    dim3 grid(all.s[s].htiles, all.s[s].NSEG, B);
    topk_kernel<<<grid, 256, 0, stream>>>(all.s[s]);
  }
  for (int s = 0; s < 3; s++) {
    int g = (B * HWs[s] + 3) / 4;
    merge_kernel<<<g, 256, 0, stream>>>(all.s[s]);
  }
  for (int s = 0; s < 3; s++) {
    int g = (B * NEs[s] + 255) / 256;
    invs_kernel<<<g, 256, 0, stream>>>(all.s[s]);
  }
  for (int s = 0; s < 3; s++)
    base_kernel<<<dim3(CV, B), 256, 0, stream>>>(all.s[s]);
  for (int s = 0; s < 3; s++) {
    int g = (B * CV * HWs[s] + 255) / 256;
    out_kernel<<<g, 256, 0, stream>>>(all.s[s]);
  }
}